// Round 9
// baseline (1102.148 us; speedup 1.0000x reference)
//
#include <hip/hip_runtime.h>
#include <hip/hip_bf16.h>

#define N_NODES 100000
#define N_EDGES 640000
#define D 128
#define NB 98              // ceil(N_NODES / 1024) scan blocks (fallback path)

// bucketed aggregation parameters
#define BSZ 64                         // nodes per bucket (power of 2)
#define NBKT 1563                      // ceil(100000 / 64)
#define NBKT_PAD 1568                  // padded to multiple of 32
#define NBLK_AC 64                     // blocks for hist/scatter kernels
#define EPB (N_EDGES / NBLK_AC)        // 10000 edges per block (exact)

typedef unsigned short ushort_t;
typedef __attribute__((ext_vector_type(8))) short short8_t;   // 8 x bf16
typedef __attribute__((ext_vector_type(4))) float floatx4;    // MFMA C/D

static __device__ __forceinline__ ushort_t f32_to_bf16(float f) {
    union { __hip_bfloat16 h; ushort_t u; } c;
    c.h = __float2bfloat16(f);          // RNE
    return c.u;
}
static __device__ __forceinline__ float bf16_to_f32(ushort_t u) {
    union { unsigned int i; float f; } c;
    c.i = ((unsigned int)u) << 16;
    return c.f;
}

// ---------------------------------------------------------------------------
// Fold the two linear layers:  Wc = Wh @ Wo ; bc = bh @ Wo + bo.
// WcT stored transposed in bf16 so the MFMA B-fragment is a 16 B load.
// ---------------------------------------------------------------------------
__global__ void combine_weights(const float* __restrict__ Wh,
                                const float* __restrict__ bh,
                                const float* __restrict__ Wo,
                                const float* __restrict__ bo,
                                ushort_t* __restrict__ WcT,
                                float* __restrict__ bc) {
    int gid = blockIdx.x * blockDim.x + threadIdx.x;
    if (gid < D * D) {
        int i = gid >> 7;
        int j = gid & 127;
        float s = 0.f;
        #pragma unroll 4
        for (int k = 0; k < D; ++k)
            s = fmaf(Wh[i * D + k], Wo[k * D + j], s);
        WcT[j * D + i] = f32_to_bf16(s);
    } else if (gid < D * D + D) {
        int j = gid - D * D;
        float s = bo[j];
        #pragma unroll 4
        for (int k = 0; k < D; ++k)
            s = fmaf(bh[k], Wo[k * D + j], s);
        bc[j] = s;
    }
}

// ---------------------------------------------------------------------------
// A: per-block histogram over dst buckets (both edge directions).
// hist[blk][bkt] = #entries block blk will emit into bucket bkt.
// ---------------------------------------------------------------------------
__global__ __launch_bounds__(1024)
void hist_k(const int* __restrict__ ra, const int* __restrict__ rb,
            int* __restrict__ hist) {
    __shared__ int h[NBKT_PAD];
    const int t = threadIdx.x;
    for (int i = t; i < NBKT_PAD; i += 1024) h[i] = 0;
    __syncthreads();
    const int base = blockIdx.x * EPB;
    for (int i = t; i < EPB; i += 1024) {
        int a = ra[base + i];
        int b = rb[base + i];
        atomicAdd(&h[a >> 6], 1);
        atomicAdd(&h[b >> 6], 1);
    }
    __syncthreads();
    int* row = hist + blockIdx.x * NBKT_PAD;
    for (int i = t; i < NBKT_PAD; i += 1024) row[i] = h[i];
}

// ---------------------------------------------------------------------------
// B1: for each bucket, exclusive-scan its 64 per-block counts (in place)
// and emit the bucket total. One wave per bucket, 4 buckets per block.
// ---------------------------------------------------------------------------
__global__ __launch_bounds__(256)
void scan_hist_k(int* __restrict__ hist, int* __restrict__ btot) {
    const int wave = threadIdx.x >> 6;
    const int lane = threadIdx.x & 63;
    const int bkt = blockIdx.x * 4 + wave;
    if (bkt >= NBKT) return;
    int v = hist[lane * NBKT_PAD + bkt];
    int s = v;
    #pragma unroll
    for (int d = 1; d < 64; d <<= 1) {
        int u = __shfl_up(s, d, 64);
        if (lane >= d) s += u;
    }
    hist[lane * NBKT_PAD + bkt] = s - v;     // exclusive within bucket
    if (lane == 63) btot[bkt] = s;
}

// ---------------------------------------------------------------------------
// B2: exclusive scan of bucket totals -> bucket segment bases. 1 wave.
// ---------------------------------------------------------------------------
__global__ __launch_bounds__(64)
void scan_bkt_k(const int* __restrict__ btot, int* __restrict__ bktbase) {
    const int lane = threadIdx.x;
    int carry = 0;
    for (int c = 0; c < NBKT; c += 64) {
        int idx = c + lane;
        int v = (idx < NBKT) ? btot[idx] : 0;
        int s = v;
        #pragma unroll
        for (int d = 1; d < 64; d <<= 1) {
            int u = __shfl_up(s, d, 64);
            if (lane >= d) s += u;
        }
        if (idx < NBKT) bktbase[idx] = carry + s - v;
        carry += __shfl(s, 63, 64);
    }
}

// ---------------------------------------------------------------------------
// C: scatter packed entries into dense per-bucket segments.
// entry = (dst & 63) << 24 | src   (src < 2^24). Same-bucket writes from a
// block land in consecutive slots -> line reuse -> no writeback blowup.
// ---------------------------------------------------------------------------
__global__ __launch_bounds__(1024)
void scatter_k(const int* __restrict__ ra, const int* __restrict__ rb,
               const int* __restrict__ hist, const int* __restrict__ bktbase,
               unsigned* __restrict__ ebuf) {
    __shared__ int cur[NBKT_PAD];
    const int t = threadIdx.x;
    const int* row = hist + blockIdx.x * NBKT_PAD;
    for (int i = t; i < NBKT; i += 1024) cur[i] = bktbase[i] + row[i];
    __syncthreads();
    const int base = blockIdx.x * EPB;
    for (int i = t; i < EPB; i += 1024) {
        int a = ra[base + i];
        int b = rb[base + i];
        int sa = atomicAdd(&cur[a >> 6], 1);
        ebuf[sa] = ((unsigned)(a & 63) << 24) | (unsigned)b;
        int sb = atomicAdd(&cur[b >> 6], 1);
        ebuf[sb] = ((unsigned)(b & 63) << 24) | (unsigned)a;
    }
}

// ---------------------------------------------------------------------------
// MFMA GEMM (16x16x32 bf16), unchanged from R8.
//   MODE 0: Ybf = bf16(A @ Wc)        MODE 1: Fout = relu(Fout @ Wc + bc)
// ---------------------------------------------------------------------------
template<int MODE>
__global__ __launch_bounds__(256)
void gemm_mfma(const float* __restrict__ A, ushort_t* __restrict__ Ybf,
               float* Fout, const ushort_t* __restrict__ WcT,
               const float* __restrict__ bc) {
    __shared__ ushort_t Ws[D][136];
    const int t = threadIdx.x;

    {
        const short8_t* src = (const short8_t*)WcT;
        #pragma unroll
        for (int i = 0; i < 8; ++i) {
            int g = t + i * 256;
            int n = g >> 4;
            int k = (g & 15) * 8;
            *(short8_t*)(&Ws[n][k]) = src[g];
        }
    }
    __syncthreads();

    const int wave = t >> 6;
    const int lane = t & 63;
    const int rowBase = (blockIdx.x * 4 + wave) * 16;
    if (rowBase >= N_NODES) return;

    const int m = rowBase + (lane & 15);
    const int kgrp = lane >> 4;
    const float* arow = (MODE == 0 ? A : (const float*)Fout) + (size_t)m * D;

    short8_t afrag[4];
    #pragma unroll
    for (int kc = 0; kc < 4; ++kc) {
        int k0 = kc * 32 + kgrp * 8;
        float4 lo = *(const float4*)(arow + k0);
        float4 hi = *(const float4*)(arow + k0 + 4);
        short8_t f;
        f[0] = (short)f32_to_bf16(lo.x);
        f[1] = (short)f32_to_bf16(lo.y);
        f[2] = (short)f32_to_bf16(lo.z);
        f[3] = (short)f32_to_bf16(lo.w);
        f[4] = (short)f32_to_bf16(hi.x);
        f[5] = (short)f32_to_bf16(hi.y);
        f[6] = (short)f32_to_bf16(hi.z);
        f[7] = (short)f32_to_bf16(hi.w);
        afrag[kc] = f;
    }

    floatx4 acc[8];
    #pragma unroll
    for (int nt = 0; nt < 8; ++nt)
        acc[nt] = (floatx4){0.f, 0.f, 0.f, 0.f};

    #pragma unroll
    for (int kc = 0; kc < 4; ++kc) {
        const int k0 = kc * 32 + kgrp * 8;
        #pragma unroll
        for (int nt = 0; nt < 8; ++nt) {
            const int n = nt * 16 + (lane & 15);
            short8_t b = *(const short8_t*)(&Ws[n][k0]);
            acc[nt] = __builtin_amdgcn_mfma_f32_16x16x32_bf16(afrag[kc], b, acc[nt], 0, 0, 0);
        }
    }

    const int orow0 = rowBase + (lane >> 4) * 4;
    const int col0 = lane & 15;
    if (MODE == 0) {
        #pragma unroll
        for (int j = 0; j < 4; ++j) {
            size_t base = (size_t)(orow0 + j) * D;
            #pragma unroll
            for (int nt = 0; nt < 8; ++nt)
                Ybf[base + nt * 16 + col0] = f32_to_bf16(acc[nt][j]);
        }
    } else {
        #pragma unroll
        for (int j = 0; j < 4; ++j) {
            size_t base = (size_t)(orow0 + j) * D;
            #pragma unroll
            for (int nt = 0; nt < 8; ++nt) {
                float v = acc[nt][j] + bc[nt * 16 + col0];
                Fout[base + nt * 16 + col0] = fmaxf(v, 0.f);
            }
        }
    }
}

// ---------------------------------------------------------------------------
// D': push aggregation per bucket. LDS accum [64][128] f32 (32 KB ->
// 4 blocks/CU, 100% occupancy). init acc = Y[own rows]; stream entry
// segment (sequential); add Y[src] rows via LDS atomics; bias+relu+store.
// ---------------------------------------------------------------------------
__global__ __launch_bounds__(512)
void agg_push_k(const ushort_t* __restrict__ Ybf, const unsigned* __restrict__ ebuf,
                const int* __restrict__ bktbase, const int* __restrict__ btot,
                const float* __restrict__ bc, float* __restrict__ out) {
    __shared__ float acc[BSZ][D];      // 32 KB
    const int bkt = blockIdx.x;
    const int t = threadIdx.x;
    const int node0 = bkt * BSZ;
    const int nn = min(BSZ, N_NODES - node0);

    {   // init: acc[i] = f32(Y[node0+i]); thread t -> node t>>3, cols (t&7)*16..+16
        int i = t >> 3;
        int c0 = (t & 7) * 16;
        if (i < nn) {
            const ushort_t* yrow = Ybf + (size_t)(node0 + i) * D + c0;
            #pragma unroll
            for (int j = 0; j < 16; j += 4) {
                ushort4 u = *(const ushort4*)(yrow + j);
                acc[i][c0 + j + 0] = bf16_to_f32(u.x);
                acc[i][c0 + j + 1] = bf16_to_f32(u.y);
                acc[i][c0 + j + 2] = bf16_to_f32(u.z);
                acc[i][c0 + j + 3] = bf16_to_f32(u.w);
            }
        }
    }
    __syncthreads();

    const int base = bktbase[bkt];
    const int cnt = btot[bkt];
    const int grp = t >> 5;            // 16 groups of 32 lanes
    const int l32 = t & 31;

    int g = grp;
    for (; g + 16 < cnt; g += 32) {    // 2-way unroll: two rows in flight
        unsigned e0 = ebuf[base + g];
        unsigned e1 = ebuf[base + g + 16];
        int s0 = e0 & 0xFFFFFF, c0 = e0 >> 24;
        int s1 = e1 & 0xFFFFFF, c1 = e1 >> 24;
        ushort4 u0 = *(const ushort4*)(Ybf + (size_t)s0 * D + l32 * 4);
        ushort4 u1 = *(const ushort4*)(Ybf + (size_t)s1 * D + l32 * 4);
        atomicAdd(&acc[c0][l32 * 4 + 0], bf16_to_f32(u0.x));
        atomicAdd(&acc[c0][l32 * 4 + 1], bf16_to_f32(u0.y));
        atomicAdd(&acc[c0][l32 * 4 + 2], bf16_to_f32(u0.z));
        atomicAdd(&acc[c0][l32 * 4 + 3], bf16_to_f32(u0.w));
        atomicAdd(&acc[c1][l32 * 4 + 0], bf16_to_f32(u1.x));
        atomicAdd(&acc[c1][l32 * 4 + 1], bf16_to_f32(u1.y));
        atomicAdd(&acc[c1][l32 * 4 + 2], bf16_to_f32(u1.z));
        atomicAdd(&acc[c1][l32 * 4 + 3], bf16_to_f32(u1.w));
    }
    if (g < cnt) {
        unsigned e0 = ebuf[base + g];
        int s0 = e0 & 0xFFFFFF, c0 = e0 >> 24;
        ushort4 u0 = *(const ushort4*)(Ybf + (size_t)s0 * D + l32 * 4);
        atomicAdd(&acc[c0][l32 * 4 + 0], bf16_to_f32(u0.x));
        atomicAdd(&acc[c0][l32 * 4 + 1], bf16_to_f32(u0.y));
        atomicAdd(&acc[c0][l32 * 4 + 2], bf16_to_f32(u0.z));
        atomicAdd(&acc[c0][l32 * 4 + 3], bf16_to_f32(u0.w));
    }
    __syncthreads();

    {   // epilogue: out = relu(acc + bc)
        int i = t >> 3;
        int c0 = (t & 7) * 16;
        if (i < nn) {
            float* orow = out + (size_t)(node0 + i) * D + c0;
            #pragma unroll
            for (int j = 0; j < 16; j += 4) {
                float4 o;
                o.x = fmaxf(acc[i][c0 + j + 0] + bc[c0 + j + 0], 0.f);
                o.y = fmaxf(acc[i][c0 + j + 1] + bc[c0 + j + 1], 0.f);
                o.z = fmaxf(acc[i][c0 + j + 2] + bc[c0 + j + 2], 0.f);
                o.w = fmaxf(acc[i][c0 + j + 3] + bc[c0 + j + 3], 0.f);
                *(float4*)(orow + j) = o;
            }
        }
    }
}

// ===========================================================================
// Fallback path (small workspace): R6/R8 CSR build + f32 gather + in-place GEMM
// ===========================================================================
__global__ __launch_bounds__(256)
void count_deg(const int* __restrict__ ra, const int* __restrict__ rb,
               int* __restrict__ cnt) {
    int e = blockIdx.x * 256 + threadIdx.x;
    if (e < N_EDGES) {
        atomicAdd(&cnt[ra[e]], 1);
        atomicAdd(&cnt[rb[e]], 1);
    }
}

__global__ __launch_bounds__(256)
void sum_blocks(const int* __restrict__ cnt, int* __restrict__ partials) {
    __shared__ int sm[256];
    int t = threadIdx.x;
    int base = blockIdx.x * 1024 + t * 4;
    int tot = 0;
    #pragma unroll
    for (int i = 0; i < 4; ++i)
        if (base + i < N_NODES) tot += cnt[base + i];
    sm[t] = tot;
    __syncthreads();
    for (int d = 128; d > 0; d >>= 1) {
        if (t < d) sm[t] += sm[t + d];
        __syncthreads();
    }
    if (t == 0) partials[blockIdx.x] = sm[0];
}

__global__ void scan_partials(int* __restrict__ partials, int* __restrict__ off) {
    if (blockIdx.x == 0 && threadIdx.x == 0) {
        int run = 0;
        for (int b = 0; b < NB; ++b) {
            int v = partials[b];
            partials[b] = run;
            run += v;
        }
        off[N_NODES] = run;
    }
}

__global__ __launch_bounds__(256)
void scan_blocks(const int* __restrict__ cnt, const int* __restrict__ partials,
                 int* __restrict__ off, int* __restrict__ cur) {
    __shared__ int sm[256];
    int t = threadIdx.x;
    int base = blockIdx.x * 1024 + t * 4;
    int c[4];
    int tot = 0;
    #pragma unroll
    for (int i = 0; i < 4; ++i) {
        c[i] = (base + i < N_NODES) ? cnt[base + i] : 0;
        tot += c[i];
    }
    sm[t] = tot;
    __syncthreads();
    for (int d = 1; d < 256; d <<= 1) {
        int v = (t >= d) ? sm[t - d] : 0;
        __syncthreads();
        sm[t] += v;
        __syncthreads();
    }
    int excl = sm[t] - tot + partials[blockIdx.x];
    #pragma unroll
    for (int i = 0; i < 4; ++i) {
        int idx = base + i;
        if (idx < N_NODES) {
            off[idx] = excl;
            cur[idx] = excl;
            excl += c[i];
        }
    }
}

__global__ __launch_bounds__(256)
void fill_adj(const int* __restrict__ ra, const int* __restrict__ rb,
              int* __restrict__ cur, int* __restrict__ adj) {
    int e = blockIdx.x * 256 + threadIdx.x;
    if (e < N_EDGES) {
        int a = ra[e];
        int b = rb[e];
        adj[atomicAdd(&cur[a], 1)] = b;
        adj[atomicAdd(&cur[b], 1)] = a;
    }
}

__global__ __launch_bounds__(256)
void gather_f32(const float* __restrict__ Xf, const int* __restrict__ off,
                const int* __restrict__ adj, float* __restrict__ out) {
    const int node = blockIdx.x * 8 + (threadIdx.x >> 5);
    const int lane = threadIdx.x & 31;
    float4 acc = *(const float4*)(Xf + (size_t)node * D + lane * 4);
    const int s = off[node];
    const int e = off[node + 1];
    int k = s;
    for (; k + 1 < e; k += 2) {
        int n0 = adj[k];
        int n1 = adj[k + 1];
        float4 v0 = *(const float4*)(Xf + (size_t)n0 * D + lane * 4);
        float4 v1 = *(const float4*)(Xf + (size_t)n1 * D + lane * 4);
        acc.x += v0.x; acc.y += v0.y; acc.z += v0.z; acc.w += v0.w;
        acc.x += v1.x; acc.y += v1.y; acc.z += v1.z; acc.w += v1.w;
    }
    if (k < e) {
        int n0 = adj[k];
        float4 v0 = *(const float4*)(Xf + (size_t)n0 * D + lane * 4);
        acc.x += v0.x; acc.y += v0.y; acc.z += v0.z; acc.w += v0.w;
    }
    *(float4*)(out + (size_t)node * D + lane * 4) = acc;
}

// ---------------------------------------------------------------------------
extern "C" void kernel_launch(void* const* d_in, const int* in_sizes, int n_in,
                              void* d_out, int out_size, void* d_ws, size_t ws_size,
                              hipStream_t stream) {
    const float* X  = (const float*)d_in[0];
    const float* Wh = (const float*)d_in[1];
    const float* bh = (const float*)d_in[2];
    const float* Wo = (const float*)d_in[3];
    const float* bo = (const float*)d_in[4];
    const int* ra   = (const int*)d_in[5];
    const int* rb   = (const int*)d_in[6];
    float* out = (float*)d_out;

    // workspace layout (main path), all 16 B aligned
    char* p = (char*)d_ws;
    ushort_t* WcT  = (ushort_t*)p; p += (size_t)D * D * 2;              // 32 KB
    float* bc      = (float*)p;    p += (size_t)D * 4;                  // 512 B
    int* hist      = (int*)p;      p += (size_t)NBLK_AC * NBKT_PAD * 4; // 401 KB
    int* btot      = (int*)p;      p += (size_t)NBKT_PAD * 4;           // 6.3 KB
    int* bktbase   = (int*)p;      p += (size_t)NBKT_PAD * 4;           // 6.3 KB
    unsigned* ebuf = (unsigned*)p; p += (size_t)2 * N_EDGES * 4;        // 5.12 MB
    ushort_t* Ybf  = (ushort_t*)p; p += (size_t)N_NODES * D * 2;        // 25.6 MB
    const size_t need = (size_t)(p - (char*)d_ws);
    const bool bigws = ws_size >= need;

    // fold weights (both paths)
    combine_weights<<<(D * D + D + 255) / 256, 256, 0, stream>>>(Wh, bh, Wo, bo, WcT, bc);

    if (bigws) {
        // GEMM-first: Y = bf16(X @ Wc)
        gemm_mfma<0><<<(N_NODES + 63) / 64, 256, 0, stream>>>(X, Ybf, nullptr, WcT, bc);
        // bucketed entry build (deterministic, no global contended atomics)
        hist_k<<<NBLK_AC, 1024, 0, stream>>>(ra, rb, hist);
        scan_hist_k<<<(NBKT + 3) / 4, 256, 0, stream>>>(hist, btot);
        scan_bkt_k<<<1, 64, 0, stream>>>(btot, bktbase);
        scatter_k<<<NBLK_AC, 1024, 0, stream>>>(ra, rb, hist, bktbase, ebuf);
        // push aggregation + bias + relu
        agg_push_k<<<NBKT, 512, 0, stream>>>(Ybf, ebuf, bktbase, btot, bc, out);
    } else {
        // fallback: CSR build + f32 gather into d_out + in-place MFMA GEMM
        char* q = (char*)d_ws;
        ushort_t* WcT2 = (ushort_t*)q; q += (size_t)D * D * 2;
        float* bc2     = (float*)q;    q += (size_t)D * 4;
        int* cnt       = (int*)q;      q += (size_t)N_NODES * 4;
        int* off       = (int*)q;      q += (size_t)(N_NODES + 4) * 4;
        int* cur       = (int*)q;      q += (size_t)N_NODES * 4;
        int* adj       = (int*)q;      q += (size_t)2 * N_EDGES * 4;
        int* partials  = (int*)q;      q += 448;
        (void)WcT2; (void)bc2;
        hipMemsetAsync(cnt, 0, N_NODES * sizeof(int), stream);
        count_deg<<<N_EDGES / 256, 256, 0, stream>>>(ra, rb, cnt);
        sum_blocks<<<NB, 256, 0, stream>>>(cnt, partials);
        scan_partials<<<1, 64, 0, stream>>>(partials, off);
        scan_blocks<<<NB, 256, 0, stream>>>(cnt, partials, off, cur);
        fill_adj<<<N_EDGES / 256, 256, 0, stream>>>(ra, rb, cur, adj);
        gather_f32<<<N_NODES / 8, 256, 0, stream>>>(X, off, adj, out);
        gemm_mfma<1><<<(N_NODES + 63) / 64, 256, 0, stream>>>(nullptr, nullptr, out, WcT, bc);
    }
}

// Round 10
// 244.598 us; speedup vs baseline: 4.5059x; 4.5059x over previous
//
#include <hip/hip_runtime.h>
#include <hip/hip_bf16.h>

#define N_NODES 100000
#define N_EDGES 640000
#define D 128
#define NB 98              // ceil(N_NODES / 1024) scan blocks (fallback path)

// bucketed entry-build parameters (R9-verbatim, measured working)
#define BSZ 64                         // nodes per bucket
#define NBKT 1563                      // ceil(100000 / 64)
#define NBKT_PAD 1568                  // padded
#define NBLK_AC 64                     // blocks for hist/scatter kernels
#define EPB (N_EDGES / NBLK_AC)        // 10000 edges per block (exact)
#define CAP 3072                       // resort LDS segment capacity (mean 819, sd 29 -> ~79 sigma)

typedef unsigned short ushort_t;
typedef __attribute__((ext_vector_type(8))) short short8_t;   // 8 x bf16
typedef __attribute__((ext_vector_type(4))) float floatx4;    // MFMA C/D

static __device__ __forceinline__ ushort_t f32_to_bf16(float f) {
    union { __hip_bfloat16 h; ushort_t u; } c;
    c.h = __float2bfloat16(f);          // RNE
    return c.u;
}
static __device__ __forceinline__ float bf16_to_f32(ushort_t u) {
    union { unsigned int i; float f; } c;
    c.i = ((unsigned int)u) << 16;
    return c.f;
}

// ---------------------------------------------------------------------------
// Fold the two linear layers:  Wc = Wh @ Wo ; bc = bh @ Wo + bo.
// ---------------------------------------------------------------------------
__global__ void combine_weights(const float* __restrict__ Wh,
                                const float* __restrict__ bh,
                                const float* __restrict__ Wo,
                                const float* __restrict__ bo,
                                ushort_t* __restrict__ WcT,
                                float* __restrict__ bc) {
    int gid = blockIdx.x * blockDim.x + threadIdx.x;
    if (gid < D * D) {
        int i = gid >> 7;
        int j = gid & 127;
        float s = 0.f;
        #pragma unroll 4
        for (int k = 0; k < D; ++k)
            s = fmaf(Wh[i * D + k], Wo[k * D + j], s);
        WcT[j * D + i] = f32_to_bf16(s);
    } else if (gid < D * D + D) {
        int j = gid - D * D;
        float s = bo[j];
        #pragma unroll 4
        for (int k = 0; k < D; ++k)
            s = fmaf(bh[k], Wo[k * D + j], s);
        bc[j] = s;
    }
}

// ---------------------------------------------------------------------------
// A: per-block histogram over dst buckets (both directions). [R9-verbatim]
// ---------------------------------------------------------------------------
__global__ __launch_bounds__(1024)
void hist_k(const int* __restrict__ ra, const int* __restrict__ rb,
            int* __restrict__ hist) {
    __shared__ int h[NBKT_PAD];
    const int t = threadIdx.x;
    for (int i = t; i < NBKT_PAD; i += 1024) h[i] = 0;
    __syncthreads();
    const int base = blockIdx.x * EPB;
    for (int i = t; i < EPB; i += 1024) {
        int a = ra[base + i];
        int b = rb[base + i];
        atomicAdd(&h[a >> 6], 1);
        atomicAdd(&h[b >> 6], 1);
    }
    __syncthreads();
    int* row = hist + blockIdx.x * NBKT_PAD;
    for (int i = t; i < NBKT_PAD; i += 1024) row[i] = h[i];
}

// ---------------------------------------------------------------------------
// B1: per bucket, exclusive-scan the 64 per-block counts; total. [R9-verbatim]
// ---------------------------------------------------------------------------
__global__ __launch_bounds__(256)
void scan_hist_k(int* __restrict__ hist, int* __restrict__ btot) {
    const int wave = threadIdx.x >> 6;
    const int lane = threadIdx.x & 63;
    const int bkt = blockIdx.x * 4 + wave;
    if (bkt >= NBKT) return;
    int v = hist[lane * NBKT_PAD + bkt];
    int s = v;
    #pragma unroll
    for (int d = 1; d < 64; d <<= 1) {
        int u = __shfl_up(s, d, 64);
        if (lane >= d) s += u;
    }
    hist[lane * NBKT_PAD + bkt] = s - v;
    if (lane == 63) btot[bkt] = s;
}

// ---------------------------------------------------------------------------
// B2: exclusive scan of bucket totals -> segment bases. [R9-verbatim]
// ---------------------------------------------------------------------------
__global__ __launch_bounds__(64)
void scan_bkt_k(const int* __restrict__ btot, int* __restrict__ bktbase) {
    const int lane = threadIdx.x;
    int carry = 0;
    for (int c = 0; c < NBKT; c += 64) {
        int idx = c + lane;
        int v = (idx < NBKT) ? btot[idx] : 0;
        int s = v;
        #pragma unroll
        for (int d = 1; d < 64; d <<= 1) {
            int u = __shfl_up(s, d, 64);
            if (lane >= d) s += u;
        }
        if (idx < NBKT) bktbase[idx] = carry + s - v;
        carry += __shfl(s, 63, 64);
    }
}

// ---------------------------------------------------------------------------
// C: scatter packed (local_dst<<24 | src) into dense bucket segments.
// [R9-verbatim] Dense per-(block,bucket) runs -> no 16x writeback blowup.
// ---------------------------------------------------------------------------
__global__ __launch_bounds__(1024)
void scatter_k(const int* __restrict__ ra, const int* __restrict__ rb,
               const int* __restrict__ hist, const int* __restrict__ bktbase,
               unsigned* __restrict__ ebuf) {
    __shared__ int cur[NBKT_PAD];
    const int t = threadIdx.x;
    const int* row = hist + blockIdx.x * NBKT_PAD;
    for (int i = t; i < NBKT; i += 1024) cur[i] = bktbase[i] + row[i];
    __syncthreads();
    const int base = blockIdx.x * EPB;
    for (int i = t; i < EPB; i += 1024) {
        int a = ra[base + i];
        int b = rb[base + i];
        int sa = atomicAdd(&cur[a >> 6], 1);
        ebuf[sa] = ((unsigned)(a & 63) << 24) | (unsigned)b;
        int sb = atomicAdd(&cur[b >> 6], 1);
        ebuf[sb] = ((unsigned)(b & 63) << 24) | (unsigned)a;
    }
}

// ---------------------------------------------------------------------------
// NEW: per-bucket in-place counting sort to exact node order + CSR offsets.
// Stage segment in LDS (reads complete before writes -> in-place safe),
// count per local node, wave-scan, write off[], place entries back as
// plain src ints. ~10 MB total traffic across 1563 blocks.
// ---------------------------------------------------------------------------
__global__ __launch_bounds__(256)
void resort_k(unsigned* __restrict__ ebuf, const int* __restrict__ bktbase,
              const int* __restrict__ btot, int* __restrict__ off) {
    __shared__ unsigned seg[CAP];
    __shared__ int cnt64[64];
    __shared__ int excl[64];
    const int bkt = blockIdx.x;
    const int t = threadIdx.x;
    const int base = bktbase[bkt];
    int cnt = btot[bkt];
    if (cnt > CAP) cnt = CAP;   // unreachable for this input (79 sigma); avoids OOB
    if (t < 64) cnt64[t] = 0;
    __syncthreads();

    // stage + count
    for (int i = t; i < cnt; i += 256) {
        unsigned e = ebuf[base + i];
        seg[i] = e;
        atomicAdd(&cnt64[e >> 24], 1);
    }
    __syncthreads();

    // exclusive scan of the 64 node counts (first wave)
    if (t < 64) {
        int v = cnt64[t];
        int s = v;
        #pragma unroll
        for (int d = 1; d < 64; d <<= 1) {
            int u = __shfl_up(s, d, 64);
            if (t >= d) s += u;
        }
        excl[t] = s - v;
        cnt64[t] = s - v;        // becomes the placement cursor
    }
    __syncthreads();

    // CSR offsets
    const int node0 = bkt * BSZ;
    if (t < 64 && node0 + t < N_NODES) off[node0 + t] = base + excl[t];
    if (bkt == NBKT - 1 && t == 0) off[N_NODES] = base + cnt;

    // place back in node order (writes only after all reads staged)
    for (int i = t; i < cnt; i += 256) {
        unsigned e = seg[i];
        int pos = atomicAdd(&cnt64[e >> 24], 1);
        ebuf[base + pos] = e & 0xFFFFFF;    // plain src index
    }
}

// ---------------------------------------------------------------------------
// MFMA GEMM (16x16x32 bf16). [R8-verbatim]
//   MODE 0: Ybf = bf16(A @ Wc)        MODE 1: Fout = relu(Fout @ Wc + bc)
// ---------------------------------------------------------------------------
template<int MODE>
__global__ __launch_bounds__(256)
void gemm_mfma(const float* __restrict__ A, ushort_t* __restrict__ Ybf,
               float* Fout, const ushort_t* __restrict__ WcT,
               const float* __restrict__ bc) {
    __shared__ ushort_t Ws[D][136];
    const int t = threadIdx.x;

    {
        const short8_t* src = (const short8_t*)WcT;
        #pragma unroll
        for (int i = 0; i < 8; ++i) {
            int g = t + i * 256;
            int n = g >> 4;
            int k = (g & 15) * 8;
            *(short8_t*)(&Ws[n][k]) = src[g];
        }
    }
    __syncthreads();

    const int wave = t >> 6;
    const int lane = t & 63;
    const int rowBase = (blockIdx.x * 4 + wave) * 16;
    if (rowBase >= N_NODES) return;

    const int m = rowBase + (lane & 15);
    const int kgrp = lane >> 4;
    const float* arow = (MODE == 0 ? A : (const float*)Fout) + (size_t)m * D;

    short8_t afrag[4];
    #pragma unroll
    for (int kc = 0; kc < 4; ++kc) {
        int k0 = kc * 32 + kgrp * 8;
        float4 lo = *(const float4*)(arow + k0);
        float4 hi = *(const float4*)(arow + k0 + 4);
        short8_t f;
        f[0] = (short)f32_to_bf16(lo.x);
        f[1] = (short)f32_to_bf16(lo.y);
        f[2] = (short)f32_to_bf16(lo.z);
        f[3] = (short)f32_to_bf16(lo.w);
        f[4] = (short)f32_to_bf16(hi.x);
        f[5] = (short)f32_to_bf16(hi.y);
        f[6] = (short)f32_to_bf16(hi.z);
        f[7] = (short)f32_to_bf16(hi.w);
        afrag[kc] = f;
    }

    floatx4 acc[8];
    #pragma unroll
    for (int nt = 0; nt < 8; ++nt)
        acc[nt] = (floatx4){0.f, 0.f, 0.f, 0.f};

    #pragma unroll
    for (int kc = 0; kc < 4; ++kc) {
        const int k0 = kc * 32 + kgrp * 8;
        #pragma unroll
        for (int nt = 0; nt < 8; ++nt) {
            const int n = nt * 16 + (lane & 15);
            short8_t b = *(const short8_t*)(&Ws[n][k0]);
            acc[nt] = __builtin_amdgcn_mfma_f32_16x16x32_bf16(afrag[kc], b, acc[nt], 0, 0, 0);
        }
    }

    const int orow0 = rowBase + (lane >> 4) * 4;
    const int col0 = lane & 15;
    if (MODE == 0) {
        #pragma unroll
        for (int j = 0; j < 4; ++j) {
            size_t base = (size_t)(orow0 + j) * D;
            #pragma unroll
            for (int nt = 0; nt < 8; ++nt)
                Ybf[base + nt * 16 + col0] = f32_to_bf16(acc[nt][j]);
        }
    } else {
        #pragma unroll
        for (int j = 0; j < 4; ++j) {
            size_t base = (size_t)(orow0 + j) * D;
            #pragma unroll
            for (int nt = 0; nt < 8; ++nt) {
                float v = acc[nt][j] + bc[nt * 16 + col0];
                Fout[base + nt * 16 + col0] = fmaxf(v, 0.f);
            }
        }
    }
}

// ---------------------------------------------------------------------------
// Pull gather over CSR (bf16 rows) + bias + relu. [R8-verbatim shape]
// ---------------------------------------------------------------------------
__global__ __launch_bounds__(256)
void gather_bf16(const ushort_t* __restrict__ Y, const int* __restrict__ off,
                 const int* __restrict__ adj, const float* __restrict__ bc,
                 float* __restrict__ out) {
    const int node = blockIdx.x * 8 + (threadIdx.x >> 5);
    const int lane = threadIdx.x & 31;
    float4 acc;
    {
        ushort4 u = *(const ushort4*)(Y + (size_t)node * D + lane * 4);
        acc.x = bf16_to_f32(u.x); acc.y = bf16_to_f32(u.y);
        acc.z = bf16_to_f32(u.z); acc.w = bf16_to_f32(u.w);
    }
    const int s = off[node];
    const int e = off[node + 1];
    int k = s;
    for (; k + 1 < e; k += 2) {
        int n0 = adj[k];
        int n1 = adj[k + 1];
        ushort4 u0 = *(const ushort4*)(Y + (size_t)n0 * D + lane * 4);
        ushort4 u1 = *(const ushort4*)(Y + (size_t)n1 * D + lane * 4);
        acc.x += bf16_to_f32(u0.x); acc.y += bf16_to_f32(u0.y);
        acc.z += bf16_to_f32(u0.z); acc.w += bf16_to_f32(u0.w);
        acc.x += bf16_to_f32(u1.x); acc.y += bf16_to_f32(u1.y);
        acc.z += bf16_to_f32(u1.z); acc.w += bf16_to_f32(u1.w);
    }
    if (k < e) {
        int n0 = adj[k];
        ushort4 u0 = *(const ushort4*)(Y + (size_t)n0 * D + lane * 4);
        acc.x += bf16_to_f32(u0.x); acc.y += bf16_to_f32(u0.y);
        acc.z += bf16_to_f32(u0.z); acc.w += bf16_to_f32(u0.w);
    }
    float4 b = *(const float4*)(bc + lane * 4);
    acc.x = fmaxf(acc.x + b.x, 0.f);
    acc.y = fmaxf(acc.y + b.y, 0.f);
    acc.z = fmaxf(acc.z + b.z, 0.f);
    acc.w = fmaxf(acc.w + b.w, 0.f);
    *(float4*)(out + (size_t)node * D + lane * 4) = acc;
}

// ===========================================================================
// Fallback path (small workspace): R8 CSR build + f32 gather + in-place GEMM
// ===========================================================================
__global__ __launch_bounds__(256)
void count_deg(const int* __restrict__ ra, const int* __restrict__ rb,
               int* __restrict__ cnt) {
    int e = blockIdx.x * 256 + threadIdx.x;
    if (e < N_EDGES) {
        atomicAdd(&cnt[ra[e]], 1);
        atomicAdd(&cnt[rb[e]], 1);
    }
}

__global__ __launch_bounds__(256)
void sum_blocks(const int* __restrict__ cnt, int* __restrict__ partials) {
    __shared__ int sm[256];
    int t = threadIdx.x;
    int base = blockIdx.x * 1024 + t * 4;
    int tot = 0;
    #pragma unroll
    for (int i = 0; i < 4; ++i)
        if (base + i < N_NODES) tot += cnt[base + i];
    sm[t] = tot;
    __syncthreads();
    for (int d = 128; d > 0; d >>= 1) {
        if (t < d) sm[t] += sm[t + d];
        __syncthreads();
    }
    if (t == 0) partials[blockIdx.x] = sm[0];
}

__global__ void scan_partials(int* __restrict__ partials, int* __restrict__ off) {
    if (blockIdx.x == 0 && threadIdx.x == 0) {
        int run = 0;
        for (int b = 0; b < NB; ++b) {
            int v = partials[b];
            partials[b] = run;
            run += v;
        }
        off[N_NODES] = run;
    }
}

__global__ __launch_bounds__(256)
void scan_blocks(const int* __restrict__ cnt, const int* __restrict__ partials,
                 int* __restrict__ off, int* __restrict__ cur) {
    __shared__ int sm[256];
    int t = threadIdx.x;
    int base = blockIdx.x * 1024 + t * 4;
    int c[4];
    int tot = 0;
    #pragma unroll
    for (int i = 0; i < 4; ++i) {
        c[i] = (base + i < N_NODES) ? cnt[base + i] : 0;
        tot += c[i];
    }
    sm[t] = tot;
    __syncthreads();
    for (int d = 1; d < 256; d <<= 1) {
        int v = (t >= d) ? sm[t - d] : 0;
        __syncthreads();
        sm[t] += v;
        __syncthreads();
    }
    int excl = sm[t] - tot + partials[blockIdx.x];
    #pragma unroll
    for (int i = 0; i < 4; ++i) {
        int idx = base + i;
        if (idx < N_NODES) {
            off[idx] = excl;
            cur[idx] = excl;
            excl += c[i];
        }
    }
}

__global__ __launch_bounds__(256)
void fill_adj(const int* __restrict__ ra, const int* __restrict__ rb,
              int* __restrict__ cur, int* __restrict__ adj) {
    int e = blockIdx.x * 256 + threadIdx.x;
    if (e < N_EDGES) {
        int a = ra[e];
        int b = rb[e];
        adj[atomicAdd(&cur[a], 1)] = b;
        adj[atomicAdd(&cur[b], 1)] = a;
    }
}

__global__ __launch_bounds__(256)
void gather_f32(const float* __restrict__ Xf, const int* __restrict__ off,
                const int* __restrict__ adj, float* __restrict__ out) {
    const int node = blockIdx.x * 8 + (threadIdx.x >> 5);
    const int lane = threadIdx.x & 31;
    float4 acc = *(const float4*)(Xf + (size_t)node * D + lane * 4);
    const int s = off[node];
    const int e = off[node + 1];
    int k = s;
    for (; k + 1 < e; k += 2) {
        int n0 = adj[k];
        int n1 = adj[k + 1];
        float4 v0 = *(const float4*)(Xf + (size_t)n0 * D + lane * 4);
        float4 v1 = *(const float4*)(Xf + (size_t)n1 * D + lane * 4);
        acc.x += v0.x; acc.y += v0.y; acc.z += v0.z; acc.w += v0.w;
        acc.x += v1.x; acc.y += v1.y; acc.z += v1.z; acc.w += v1.w;
    }
    if (k < e) {
        int n0 = adj[k];
        float4 v0 = *(const float4*)(Xf + (size_t)n0 * D + lane * 4);
        acc.x += v0.x; acc.y += v0.y; acc.z += v0.z; acc.w += v0.w;
    }
    *(float4*)(out + (size_t)node * D + lane * 4) = acc;
}

// ---------------------------------------------------------------------------
extern "C" void kernel_launch(void* const* d_in, const int* in_sizes, int n_in,
                              void* d_out, int out_size, void* d_ws, size_t ws_size,
                              hipStream_t stream) {
    const float* X  = (const float*)d_in[0];
    const float* Wh = (const float*)d_in[1];
    const float* bh = (const float*)d_in[2];
    const float* Wo = (const float*)d_in[3];
    const float* bo = (const float*)d_in[4];
    const int* ra   = (const int*)d_in[5];
    const int* rb   = (const int*)d_in[6];
    float* out = (float*)d_out;

    // workspace layout (main path) — need ~30.8 MB < R8's proven 31.3 MB
    char* p = (char*)d_ws;
    ushort_t* WcT  = (ushort_t*)p; p += (size_t)D * D * 2;              // 32 KB
    float* bc      = (float*)p;    p += (size_t)D * 4;                  // 512 B
    int* hist      = (int*)p;      p += (size_t)NBLK_AC * NBKT_PAD * 4; // 401 KB
    int* btot      = (int*)p;      p += (size_t)NBKT_PAD * 4;           // 6.3 KB
    int* bktbase   = (int*)p;      p += (size_t)NBKT_PAD * 4;           // 6.3 KB
    int* off       = (int*)p;      p += (size_t)(N_NODES + 4) * 4;      // 400 KB
    unsigned* ebuf = (unsigned*)p; p += (size_t)2 * N_EDGES * 4;        // 5.12 MB
    ushort_t* Ybf  = (ushort_t*)p; p += (size_t)N_NODES * D * 2;        // 25.6 MB
    const size_t need = (size_t)(p - (char*)d_ws);
    const bool bigws = ws_size >= need;

    combine_weights<<<(D * D + D + 255) / 256, 256, 0, stream>>>(Wh, bh, Wo, bo, WcT, bc);

    if (bigws) {
        // GEMM-first: Y = bf16(X @ Wc)
        gemm_mfma<0><<<(N_NODES + 63) / 64, 256, 0, stream>>>(X, Ybf, nullptr, WcT, bc);
        // bucketed entry build (dense writes) -> in-place node sort + CSR
        hist_k<<<NBLK_AC, 1024, 0, stream>>>(ra, rb, hist);
        scan_hist_k<<<(NBKT + 3) / 4, 256, 0, stream>>>(hist, btot);
        scan_bkt_k<<<1, 64, 0, stream>>>(btot, bktbase);
        scatter_k<<<NBLK_AC, 1024, 0, stream>>>(ra, rb, hist, bktbase, ebuf);
        resort_k<<<NBKT, 256, 0, stream>>>(ebuf, bktbase, btot, off);
        // pull gather + bias + relu (proven R8 shape; adj == resorted ebuf)
        gather_bf16<<<N_NODES / 8, 256, 0, stream>>>(Ybf, off, (const int*)ebuf, bc, out);
    } else {
        // fallback: R8 CSR build + f32 gather into d_out + in-place MFMA GEMM
        char* q = (char*)d_ws;
        ushort_t* WcT2 = (ushort_t*)q; q += (size_t)D * D * 2;
        float* bc2     = (float*)q;    q += (size_t)D * 4;
        int* cnt       = (int*)q;      q += (size_t)N_NODES * 4;
        int* offF      = (int*)q;      q += (size_t)(N_NODES + 4) * 4;
        int* cur       = (int*)q;      q += (size_t)N_NODES * 4;
        int* adj       = (int*)q;      q += (size_t)2 * N_EDGES * 4;
        int* partials  = (int*)q;      q += 448;
        (void)WcT2; (void)bc2;
        hipMemsetAsync(cnt, 0, N_NODES * sizeof(int), stream);
        count_deg<<<N_EDGES / 256, 256, 0, stream>>>(ra, rb, cnt);
        sum_blocks<<<NB, 256, 0, stream>>>(cnt, partials);
        scan_partials<<<1, 64, 0, stream>>>(partials, offF);
        scan_blocks<<<NB, 256, 0, stream>>>(cnt, partials, offF, cur);
        fill_adj<<<N_EDGES / 256, 256, 0, stream>>>(ra, rb, cur, adj);
        gather_f32<<<N_NODES / 8, 256, 0, stream>>>(X, offF, adj, out);
        gemm_mfma<1><<<(N_NODES + 63) / 64, 256, 0, stream>>>(nullptr, nullptr, out, WcT, bc);
    }
}

// Round 14
// 242.454 us; speedup vs baseline: 4.5458x; 1.0088x over previous
//
#include <hip/hip_runtime.h>
#include <hip/hip_bf16.h>

#define N_NODES 100000
#define N_EDGES 640000
#define D 128
#define NB 98              // ceil(N_NODES / 1024) scan blocks (fallback path)

// bucketed entry-build parameters (R9/R10-verbatim, measured working)
#define BSZ 64                         // nodes per bucket
#define NBKT 1563                      // ceil(100000 / 64)
#define NBKT_PAD 1568                  // padded
#define NBLK_AC 64                     // blocks for hist/scatter kernels
#define EPB (N_EDGES / NBLK_AC)        // 10000 edges per block (exact)
#define CAP 3072                       // LDS segment capacity (mean 819, sd 29)

typedef unsigned short ushort_t;
typedef __attribute__((ext_vector_type(8))) short short8_t;   // 8 x bf16
typedef __attribute__((ext_vector_type(4))) float floatx4;    // MFMA C/D

static __device__ __forceinline__ ushort_t f32_to_bf16(float f) {
    union { __hip_bfloat16 h; ushort_t u; } c;
    c.h = __float2bfloat16(f);          // RNE
    return c.u;
}
static __device__ __forceinline__ float bf16_to_f32(ushort_t u) {
    union { unsigned int i; float f; } c;
    c.i = ((unsigned int)u) << 16;
    return c.f;
}

// ---------------------------------------------------------------------------
// Fold the two linear layers:  Wc = Wh @ Wo ; bc = bh @ Wo + bo.
// ---------------------------------------------------------------------------
__global__ void combine_weights(const float* __restrict__ Wh,
                                const float* __restrict__ bh,
                                const float* __restrict__ Wo,
                                const float* __restrict__ bo,
                                ushort_t* __restrict__ WcT,
                                float* __restrict__ bc) {
    int gid = blockIdx.x * blockDim.x + threadIdx.x;
    if (gid < D * D) {
        int i = gid >> 7;
        int j = gid & 127;
        float s = 0.f;
        #pragma unroll 4
        for (int k = 0; k < D; ++k)
            s = fmaf(Wh[i * D + k], Wo[k * D + j], s);
        WcT[j * D + i] = f32_to_bf16(s);
    } else if (gid < D * D + D) {
        int j = gid - D * D;
        float s = bo[j];
        #pragma unroll 4
        for (int k = 0; k < D; ++k)
            s = fmaf(bh[k], Wo[k * D + j], s);
        bc[j] = s;
    }
}

// ---------------------------------------------------------------------------
// A: per-block histogram over dst buckets (both directions). [R10-verbatim]
// ---------------------------------------------------------------------------
__global__ __launch_bounds__(1024)
void hist_k(const int* __restrict__ ra, const int* __restrict__ rb,
            int* __restrict__ hist) {
    __shared__ int h[NBKT_PAD];
    const int t = threadIdx.x;
    for (int i = t; i < NBKT_PAD; i += 1024) h[i] = 0;
    __syncthreads();
    const int base = blockIdx.x * EPB;
    for (int i = t; i < EPB; i += 1024) {
        int a = ra[base + i];
        int b = rb[base + i];
        atomicAdd(&h[a >> 6], 1);
        atomicAdd(&h[b >> 6], 1);
    }
    __syncthreads();
    int* row = hist + blockIdx.x * NBKT_PAD;
    for (int i = t; i < NBKT_PAD; i += 1024) row[i] = h[i];
}

// ---------------------------------------------------------------------------
// B1: per bucket, exclusive-scan the 64 per-block counts; total. [R10-verbatim]
// ---------------------------------------------------------------------------
__global__ __launch_bounds__(256)
void scan_hist_k(int* __restrict__ hist, int* __restrict__ btot) {
    const int wave = threadIdx.x >> 6;
    const int lane = threadIdx.x & 63;
    const int bkt = blockIdx.x * 4 + wave;
    if (bkt >= NBKT) return;
    int v = hist[lane * NBKT_PAD + bkt];
    int s = v;
    #pragma unroll
    for (int d = 1; d < 64; d <<= 1) {
        int u = __shfl_up(s, d, 64);
        if (lane >= d) s += u;
    }
    hist[lane * NBKT_PAD + bkt] = s - v;
    if (lane == 63) btot[bkt] = s;
}

// ---------------------------------------------------------------------------
// B2: exclusive scan of bucket totals -> segment bases. [R10-verbatim]
// ---------------------------------------------------------------------------
__global__ __launch_bounds__(64)
void scan_bkt_k(const int* __restrict__ btot, int* __restrict__ bktbase) {
    const int lane = threadIdx.x;
    int carry = 0;
    for (int c = 0; c < NBKT; c += 64) {
        int idx = c + lane;
        int v = (idx < NBKT) ? btot[idx] : 0;
        int s = v;
        #pragma unroll
        for (int d = 1; d < 64; d <<= 1) {
            int u = __shfl_up(s, d, 64);
            if (lane >= d) s += u;
        }
        if (idx < NBKT) bktbase[idx] = carry + s - v;
        carry += __shfl(s, 63, 64);
    }
}

// ---------------------------------------------------------------------------
// C: scatter packed (local_dst<<24 | src) into dense bucket segments.
// [R10-verbatim] Dense per-(block,bucket) runs -> no writeback blowup.
// ---------------------------------------------------------------------------
__global__ __launch_bounds__(1024)
void scatter_k(const int* __restrict__ ra, const int* __restrict__ rb,
               const int* __restrict__ hist, const int* __restrict__ bktbase,
               unsigned* __restrict__ ebuf) {
    __shared__ int cur[NBKT_PAD];
    const int t = threadIdx.x;
    const int* row = hist + blockIdx.x * NBKT_PAD;
    for (int i = t; i < NBKT; i += 1024) cur[i] = bktbase[i] + row[i];
    __syncthreads();
    const int base = blockIdx.x * EPB;
    for (int i = t; i < EPB; i += 1024) {
        int a = ra[base + i];
        int b = rb[base + i];
        int sa = atomicAdd(&cur[a >> 6], 1);
        ebuf[sa] = ((unsigned)(a & 63) << 24) | (unsigned)b;
        int sb = atomicAdd(&cur[b >> 6], 1);
        ebuf[sb] = ((unsigned)(b & 63) << 24) | (unsigned)a;
    }
}

// ---------------------------------------------------------------------------
// MFMA GEMM (16x16x32 bf16). [R8/R10-verbatim]
//   MODE 0: Ybf = bf16(A @ Wc)        MODE 1: Fout = relu(Fout @ Wc + bc)
// ---------------------------------------------------------------------------
template<int MODE>
__global__ __launch_bounds__(256)
void gemm_mfma(const float* __restrict__ A, ushort_t* __restrict__ Ybf,
               float* Fout, const ushort_t* __restrict__ WcT,
               const float* __restrict__ bc) {
    __shared__ ushort_t Ws[D][136];
    const int t = threadIdx.x;

    {
        const short8_t* src = (const short8_t*)WcT;
        #pragma unroll
        for (int i = 0; i < 8; ++i) {
            int g = t + i * 256;
            int n = g >> 4;
            int k = (g & 15) * 8;
            *(short8_t*)(&Ws[n][k]) = src[g];
        }
    }
    __syncthreads();

    const int wave = t >> 6;
    const int lane = t & 63;
    const int rowBase = (blockIdx.x * 4 + wave) * 16;
    if (rowBase >= N_NODES) return;

    const int m = rowBase + (lane & 15);
    const int kgrp = lane >> 4;
    const float* arow = (MODE == 0 ? A : (const float*)Fout) + (size_t)m * D;

    short8_t afrag[4];
    #pragma unroll
    for (int kc = 0; kc < 4; ++kc) {
        int k0 = kc * 32 + kgrp * 8;
        float4 lo = *(const float4*)(arow + k0);
        float4 hi = *(const float4*)(arow + k0 + 4);
        short8_t f;
        f[0] = (short)f32_to_bf16(lo.x);
        f[1] = (short)f32_to_bf16(lo.y);
        f[2] = (short)f32_to_bf16(lo.z);
        f[3] = (short)f32_to_bf16(lo.w);
        f[4] = (short)f32_to_bf16(hi.x);
        f[5] = (short)f32_to_bf16(hi.y);
        f[6] = (short)f32_to_bf16(hi.z);
        f[7] = (short)f32_to_bf16(hi.w);
        afrag[kc] = f;
    }

    floatx4 acc[8];
    #pragma unroll
    for (int nt = 0; nt < 8; ++nt)
        acc[nt] = (floatx4){0.f, 0.f, 0.f, 0.f};

    #pragma unroll
    for (int kc = 0; kc < 4; ++kc) {
        const int k0 = kc * 32 + kgrp * 8;
        #pragma unroll
        for (int nt = 0; nt < 8; ++nt) {
            const int n = nt * 16 + (lane & 15);
            short8_t b = *(const short8_t*)(&Ws[n][k0]);
            acc[nt] = __builtin_amdgcn_mfma_f32_16x16x32_bf16(afrag[kc], b, acc[nt], 0, 0, 0);
        }
    }

    const int orow0 = rowBase + (lane >> 4) * 4;
    const int col0 = lane & 15;
    if (MODE == 0) {
        #pragma unroll
        for (int j = 0; j < 4; ++j) {
            size_t base = (size_t)(orow0 + j) * D;
            #pragma unroll
            for (int nt = 0; nt < 8; ++nt)
                Ybf[base + nt * 16 + col0] = f32_to_bf16(acc[nt][j]);
        }
    } else {
        #pragma unroll
        for (int j = 0; j < 4; ++j) {
            size_t base = (size_t)(orow0 + j) * D;
            #pragma unroll
            for (int nt = 0; nt < 8; ++nt) {
                float v = acc[nt][j] + bc[nt * 16 + col0];
                Fout[base + nt * 16 + col0] = fmaxf(v, 0.f);
            }
        }
    }
}

// ---------------------------------------------------------------------------
// Fused per-bucket counting-sort (in LDS) + pull gather + bias + relu.
// One block per 64-node bucket. Stage the bucket's unsorted entries
// (dst_local<<24 | src) in LDS, build per-node lists in LDS (no global
// sorted-adj writeback, no off[]), then gather: 8 groups x 32 lanes,
// group g handles nodes v = g, g+8, ... of the bucket.
// LDS: seg 12KB + slist 12KB + 3x64 ints = 24.6KB -> 6 blocks/CU.
// ---------------------------------------------------------------------------
__global__ __launch_bounds__(256)
void bucket_gather_k(const ushort_t* __restrict__ Ybf,
                     const unsigned* __restrict__ ebuf,
                     const int* __restrict__ bktbase,
                     const int* __restrict__ btot,
                     const float* __restrict__ bc,
                     float* __restrict__ out) {
    __shared__ unsigned seg[CAP];
    __shared__ unsigned slist[CAP];
    __shared__ int cnt64[64];      // per-node counts (pass 1, then read-only)
    __shared__ int start64[64];    // exclusive scan
    __shared__ int cur64[64];      // placement cursor
    const int bkt = blockIdx.x;
    const int t = threadIdx.x;
    const int base = bktbase[bkt];
    int cnt = btot[bkt];
    if (cnt > CAP) cnt = CAP;      // unreachable (79 sigma); OOB guard only

    if (t < 64) cnt64[t] = 0;
    __syncthreads();

    // stage + count
    for (int i = t; i < cnt; i += 256) {
        unsigned e = ebuf[base + i];
        seg[i] = e;
        atomicAdd(&cnt64[e >> 24], 1);
    }
    __syncthreads();

    // exclusive scan of 64 counts (wave 0)
    if (t < 64) {
        int v = cnt64[t];
        int s = v;
        #pragma unroll
        for (int d = 1; d < 64; d <<= 1) {
            int u = __shfl_up(s, d, 64);
            if (t >= d) s += u;
        }
        start64[t] = s - v;
        cur64[t] = s - v;
    }
    __syncthreads();

    // place srcs in node order (LDS only)
    for (int i = t; i < cnt; i += 256) {
        unsigned e = seg[i];
        int pos = atomicAdd(&cur64[e >> 24], 1);
        slist[pos] = e & 0xFFFFFFu;
    }
    __syncthreads();

    // gather: group g -> nodes v = g, g+8, ...
    const int g = t >> 5;
    const int l = t & 31;
    const int node0 = bkt * BSZ;
    float4 b4 = *(const float4*)(bc + l * 4);
    for (int v = g; v < BSZ; v += 8) {
        const int node = node0 + v;
        if (node >= N_NODES) break;          // only last bucket
        float4 acc;
        {
            ushort4 u = *(const ushort4*)(Ybf + (size_t)node * D + l * 4);
            acc.x = bf16_to_f32(u.x); acc.y = bf16_to_f32(u.y);
            acc.z = bf16_to_f32(u.z); acc.w = bf16_to_f32(u.w);
        }
        const int s = start64[v];
        const int e = s + cnt64[v];
        int k = s;
        for (; k + 1 < e; k += 2) {          // 2 rows in flight
            int n0 = slist[k];
            int n1 = slist[k + 1];
            ushort4 u0 = *(const ushort4*)(Ybf + (size_t)n0 * D + l * 4);
            ushort4 u1 = *(const ushort4*)(Ybf + (size_t)n1 * D + l * 4);
            acc.x += bf16_to_f32(u0.x); acc.y += bf16_to_f32(u0.y);
            acc.z += bf16_to_f32(u0.z); acc.w += bf16_to_f32(u0.w);
            acc.x += bf16_to_f32(u1.x); acc.y += bf16_to_f32(u1.y);
            acc.z += bf16_to_f32(u1.z); acc.w += bf16_to_f32(u1.w);
        }
        if (k < e) {
            int n0 = slist[k];
            ushort4 u0 = *(const ushort4*)(Ybf + (size_t)n0 * D + l * 4);
            acc.x += bf16_to_f32(u0.x); acc.y += bf16_to_f32(u0.y);
            acc.z += bf16_to_f32(u0.z); acc.w += bf16_to_f32(u0.w);
        }
        acc.x = fmaxf(acc.x + b4.x, 0.f);
        acc.y = fmaxf(acc.y + b4.y, 0.f);
        acc.z = fmaxf(acc.z + b4.z, 0.f);
        acc.w = fmaxf(acc.w + b4.w, 0.f);
        *(float4*)(out + (size_t)node * D + l * 4) = acc;
    }
}

// ===========================================================================
// Fallback path (small workspace): R8 CSR build + f32 gather + in-place GEMM
// ===========================================================================
__global__ __launch_bounds__(256)
void count_deg(const int* __restrict__ ra, const int* __restrict__ rb,
               int* __restrict__ cnt) {
    int e = blockIdx.x * 256 + threadIdx.x;
    if (e < N_EDGES) {
        atomicAdd(&cnt[ra[e]], 1);
        atomicAdd(&cnt[rb[e]], 1);
    }
}

__global__ __launch_bounds__(256)
void sum_blocks(const int* __restrict__ cnt, int* __restrict__ partials) {
    __shared__ int sm[256];
    int t = threadIdx.x;
    int base = blockIdx.x * 1024 + t * 4;
    int tot = 0;
    #pragma unroll
    for (int i = 0; i < 4; ++i)
        if (base + i < N_NODES) tot += cnt[base + i];
    sm[t] = tot;
    __syncthreads();
    for (int d = 128; d > 0; d >>= 1) {
        if (t < d) sm[t] += sm[t + d];
        __syncthreads();
    }
    if (t == 0) partials[blockIdx.x] = sm[0];
}

__global__ void scan_partials(int* __restrict__ partials, int* __restrict__ off) {
    if (blockIdx.x == 0 && threadIdx.x == 0) {
        int run = 0;
        for (int b = 0; b < NB; ++b) {
            int v = partials[b];
            partials[b] = run;
            run += v;
        }
        off[N_NODES] = run;
    }
}

__global__ __launch_bounds__(256)
void scan_blocks(const int* __restrict__ cnt, const int* __restrict__ partials,
                 int* __restrict__ off, int* __restrict__ cur) {
    __shared__ int sm[256];
    int t = threadIdx.x;
    int base = blockIdx.x * 1024 + t * 4;
    int c[4];
    int tot = 0;
    #pragma unroll
    for (int i = 0; i < 4; ++i) {
        c[i] = (base + i < N_NODES) ? cnt[base + i] : 0;
        tot += c[i];
    }
    sm[t] = tot;
    __syncthreads();
    for (int d = 1; d < 256; d <<= 1) {
        int v = (t >= d) ? sm[t - d] : 0;
        __syncthreads();
        sm[t] += v;
        __syncthreads();
    }
    int excl = sm[t] - tot + partials[blockIdx.x];
    #pragma unroll
    for (int i = 0; i < 4; ++i) {
        int idx = base + i;
        if (idx < N_NODES) {
            off[idx] = excl;
            cur[idx] = excl;
            excl += c[i];
        }
    }
}

__global__ __launch_bounds__(256)
void fill_adj(const int* __restrict__ ra, const int* __restrict__ rb,
              int* __restrict__ cur, int* __restrict__ adj) {
    int e = blockIdx.x * 256 + threadIdx.x;
    if (e < N_EDGES) {
        int a = ra[e];
        int b = rb[e];
        adj[atomicAdd(&cur[a], 1)] = b;
        adj[atomicAdd(&cur[b], 1)] = a;
    }
}

__global__ __launch_bounds__(256)
void gather_f32(const float* __restrict__ Xf, const int* __restrict__ off,
                const int* __restrict__ adj, float* __restrict__ out) {
    const int node = blockIdx.x * 8 + (threadIdx.x >> 5);
    const int lane = threadIdx.x & 31;
    float4 acc = *(const float4*)(Xf + (size_t)node * D + lane * 4);
    const int s = off[node];
    const int e = off[node + 1];
    int k = s;
    for (; k + 1 < e; k += 2) {
        int n0 = adj[k];
        int n1 = adj[k + 1];
        float4 v0 = *(const float4*)(Xf + (size_t)n0 * D + lane * 4);
        float4 v1 = *(const float4*)(Xf + (size_t)n1 * D + lane * 4);
        acc.x += v0.x; acc.y += v0.y; acc.z += v0.z; acc.w += v0.w;
        acc.x += v1.x; acc.y += v1.y; acc.z += v1.z; acc.w += v1.w;
    }
    if (k < e) {
        int n0 = adj[k];
        float4 v0 = *(const float4*)(Xf + (size_t)n0 * D + lane * 4);
        acc.x += v0.x; acc.y += v0.y; acc.z += v0.z; acc.w += v0.w;
    }
    *(float4*)(out + (size_t)node * D + lane * 4) = acc;
}

// ---------------------------------------------------------------------------
extern "C" void kernel_launch(void* const* d_in, const int* in_sizes, int n_in,
                              void* d_out, int out_size, void* d_ws, size_t ws_size,
                              hipStream_t stream) {
    const float* X  = (const float*)d_in[0];
    const float* Wh = (const float*)d_in[1];
    const float* bh = (const float*)d_in[2];
    const float* Wo = (const float*)d_in[3];
    const float* bo = (const float*)d_in[4];
    const int* ra   = (const int*)d_in[5];
    const int* rb   = (const int*)d_in[6];
    float* out = (float*)d_out;

    // workspace layout (main path) — ~30.4 MB, under R10's proven budget
    char* p = (char*)d_ws;
    ushort_t* WcT  = (ushort_t*)p; p += (size_t)D * D * 2;              // 32 KB
    float* bc      = (float*)p;    p += (size_t)D * 4;                  // 512 B
    int* hist      = (int*)p;      p += (size_t)NBLK_AC * NBKT_PAD * 4; // 401 KB
    int* btot      = (int*)p;      p += (size_t)NBKT_PAD * 4;           // 6.3 KB
    int* bktbase   = (int*)p;      p += (size_t)NBKT_PAD * 4;           // 6.3 KB
    unsigned* ebuf = (unsigned*)p; p += (size_t)2 * N_EDGES * 4;        // 5.12 MB
    ushort_t* Ybf  = (ushort_t*)p; p += (size_t)N_NODES * D * 2;        // 25.6 MB
    const size_t need = (size_t)(p - (char*)d_ws);
    const bool bigws = ws_size >= need;

    combine_weights<<<(D * D + D + 255) / 256, 256, 0, stream>>>(Wh, bh, Wo, bo, WcT, bc);

    if (bigws) {
        // GEMM-first: Y = bf16(X @ Wc)
        gemm_mfma<0><<<(N_NODES + 63) / 64, 256, 0, stream>>>(X, Ybf, nullptr, WcT, bc);
        // bucketed entry build (dense writes)
        hist_k<<<NBLK_AC, 1024, 0, stream>>>(ra, rb, hist);
        scan_hist_k<<<(NBKT + 3) / 4, 256, 0, stream>>>(hist, btot);
        scan_bkt_k<<<1, 64, 0, stream>>>(btot, bktbase);
        scatter_k<<<NBLK_AC, 1024, 0, stream>>>(ra, rb, hist, bktbase, ebuf);
        // fused LDS sort + pull gather + bias + relu
        bucket_gather_k<<<NBKT, 256, 0, stream>>>(Ybf, ebuf, bktbase, btot, bc, out);
    } else {
        // fallback: R8 CSR build + f32 gather into d_out + in-place MFMA GEMM
        char* q = (char*)d_ws;
        ushort_t* WcT2 = (ushort_t*)q; q += (size_t)D * D * 2;
        float* bc2     = (float*)q;    q += (size_t)D * 4;
        int* cnt       = (int*)q;      q += (size_t)N_NODES * 4;
        int* offF      = (int*)q;      q += (size_t)(N_NODES + 4) * 4;
        int* cur       = (int*)q;      q += (size_t)N_NODES * 4;
        int* adj       = (int*)q;      q += (size_t)2 * N_EDGES * 4;
        int* partials  = (int*)q;      q += 448;
        (void)WcT2; (void)bc2;
        hipMemsetAsync(cnt, 0, N_NODES * sizeof(int), stream);
        count_deg<<<N_EDGES / 256, 256, 0, stream>>>(ra, rb, cnt);
        sum_blocks<<<NB, 256, 0, stream>>>(cnt, partials);
        scan_partials<<<1, 64, 0, stream>>>(partials, offF);
        scan_blocks<<<NB, 256, 0, stream>>>(cnt, partials, offF, cur);
        fill_adj<<<N_EDGES / 256, 256, 0, stream>>>(ra, rb, cur, adj);
        gather_f32<<<N_NODES / 8, 256, 0, stream>>>(X, offF, adj, out);
        gemm_mfma<1><<<(N_NODES + 63) / 64, 256, 0, stream>>>(nullptr, nullptr, out, WcT, bc);
    }
}

// Round 15
// 218.261 us; speedup vs baseline: 5.0497x; 1.1108x over previous
//
#include <hip/hip_runtime.h>
#include <hip/hip_bf16.h>

#define N_NODES 100000
#define N_EDGES 640000
#define D 128
#define NB 98              // ceil(N_NODES / 1024) scan blocks (fallback path)

// bucketed entry-build parameters (R9/R10-verbatim, measured working)
#define BSZ 64                         // nodes per bucket
#define NBKT 1563                      // ceil(100000 / 64)
#define NBKT_PAD 1568                  // padded
#define NBLK_AC 64                     // blocks for hist/scatter kernels
#define EPB (N_EDGES / NBLK_AC)        // 10000 edges per block (exact)
#define CAP 3072                       // LDS slist capacity (mean 819, sd 29)

typedef unsigned short ushort_t;
typedef __attribute__((ext_vector_type(8))) short short8_t;   // 8 x bf16
typedef __attribute__((ext_vector_type(4))) float floatx4;    // MFMA C/D

static __device__ __forceinline__ ushort_t f32_to_bf16(float f) {
    union { __hip_bfloat16 h; ushort_t u; } c;
    c.h = __float2bfloat16(f);          // RNE
    return c.u;
}
static __device__ __forceinline__ float bf16_to_f32(ushort_t u) {
    union { unsigned int i; float f; } c;
    c.i = ((unsigned int)u) << 16;
    return c.f;
}

// ---------------------------------------------------------------------------
// Fold the two linear layers:  Wc = Wh @ Wo ; bc = bh @ Wo + bo.
// ---------------------------------------------------------------------------
__global__ void combine_weights(const float* __restrict__ Wh,
                                const float* __restrict__ bh,
                                const float* __restrict__ Wo,
                                const float* __restrict__ bo,
                                ushort_t* __restrict__ WcT,
                                float* __restrict__ bc) {
    int gid = blockIdx.x * blockDim.x + threadIdx.x;
    if (gid < D * D) {
        int i = gid >> 7;
        int j = gid & 127;
        float s = 0.f;
        #pragma unroll 4
        for (int k = 0; k < D; ++k)
            s = fmaf(Wh[i * D + k], Wo[k * D + j], s);
        WcT[j * D + i] = f32_to_bf16(s);
    } else if (gid < D * D + D) {
        int j = gid - D * D;
        float s = bo[j];
        #pragma unroll 4
        for (int k = 0; k < D; ++k)
            s = fmaf(bh[k], Wo[k * D + j], s);
        bc[j] = s;
    }
}

// ---------------------------------------------------------------------------
// A: per-block histogram over dst buckets (both directions). [R10-verbatim]
// ---------------------------------------------------------------------------
__global__ __launch_bounds__(1024)
void hist_k(const int* __restrict__ ra, const int* __restrict__ rb,
            int* __restrict__ hist) {
    __shared__ int h[NBKT_PAD];
    const int t = threadIdx.x;
    for (int i = t; i < NBKT_PAD; i += 1024) h[i] = 0;
    __syncthreads();
    const int base = blockIdx.x * EPB;
    for (int i = t; i < EPB; i += 1024) {
        int a = ra[base + i];
        int b = rb[base + i];
        atomicAdd(&h[a >> 6], 1);
        atomicAdd(&h[b >> 6], 1);
    }
    __syncthreads();
    int* row = hist + blockIdx.x * NBKT_PAD;
    for (int i = t; i < NBKT_PAD; i += 1024) row[i] = h[i];
}

// ---------------------------------------------------------------------------
// B1: per bucket, exclusive-scan the 64 per-block counts; total. [R10-verbatim]
// ---------------------------------------------------------------------------
__global__ __launch_bounds__(256)
void scan_hist_k(int* __restrict__ hist, int* __restrict__ btot) {
    const int wave = threadIdx.x >> 6;
    const int lane = threadIdx.x & 63;
    const int bkt = blockIdx.x * 4 + wave;
    if (bkt >= NBKT) return;
    int v = hist[lane * NBKT_PAD + bkt];
    int s = v;
    #pragma unroll
    for (int d = 1; d < 64; d <<= 1) {
        int u = __shfl_up(s, d, 64);
        if (lane >= d) s += u;
    }
    hist[lane * NBKT_PAD + bkt] = s - v;
    if (lane == 63) btot[bkt] = s;
}

// ---------------------------------------------------------------------------
// B2: exclusive scan of bucket totals -> segment bases. [R10-verbatim]
// ---------------------------------------------------------------------------
__global__ __launch_bounds__(64)
void scan_bkt_k(const int* __restrict__ btot, int* __restrict__ bktbase) {
    const int lane = threadIdx.x;
    int carry = 0;
    for (int c = 0; c < NBKT; c += 64) {
        int idx = c + lane;
        int v = (idx < NBKT) ? btot[idx] : 0;
        int s = v;
        #pragma unroll
        for (int d = 1; d < 64; d <<= 1) {
            int u = __shfl_up(s, d, 64);
            if (lane >= d) s += u;
        }
        if (idx < NBKT) bktbase[idx] = carry + s - v;
        carry += __shfl(s, 63, 64);
    }
}

// ---------------------------------------------------------------------------
// C: scatter packed (local_dst<<24 | src) into dense bucket segments.
// [R10-verbatim] Dense per-(block,bucket) runs -> no writeback blowup.
// ---------------------------------------------------------------------------
__global__ __launch_bounds__(1024)
void scatter_k(const int* __restrict__ ra, const int* __restrict__ rb,
               const int* __restrict__ hist, const int* __restrict__ bktbase,
               unsigned* __restrict__ ebuf) {
    __shared__ int cur[NBKT_PAD];
    const int t = threadIdx.x;
    const int* row = hist + blockIdx.x * NBKT_PAD;
    for (int i = t; i < NBKT; i += 1024) cur[i] = bktbase[i] + row[i];
    __syncthreads();
    const int base = blockIdx.x * EPB;
    for (int i = t; i < EPB; i += 1024) {
        int a = ra[base + i];
        int b = rb[base + i];
        int sa = atomicAdd(&cur[a >> 6], 1);
        ebuf[sa] = ((unsigned)(a & 63) << 24) | (unsigned)b;
        int sb = atomicAdd(&cur[b >> 6], 1);
        ebuf[sb] = ((unsigned)(b & 63) << 24) | (unsigned)a;
    }
}

// ---------------------------------------------------------------------------
// MFMA GEMM (16x16x32 bf16). [R8/R10-verbatim]
//   MODE 0: Ybf = bf16(A @ Wc)        MODE 1: Fout = relu(Fout @ Wc + bc)
// ---------------------------------------------------------------------------
template<int MODE>
__global__ __launch_bounds__(256)
void gemm_mfma(const float* __restrict__ A, ushort_t* __restrict__ Ybf,
               float* Fout, const ushort_t* __restrict__ WcT,
               const float* __restrict__ bc) {
    __shared__ ushort_t Ws[D][136];
    const int t = threadIdx.x;

    {
        const short8_t* src = (const short8_t*)WcT;
        #pragma unroll
        for (int i = 0; i < 8; ++i) {
            int g = t + i * 256;
            int n = g >> 4;
            int k = (g & 15) * 8;
            *(short8_t*)(&Ws[n][k]) = src[g];
        }
    }
    __syncthreads();

    const int wave = t >> 6;
    const int lane = t & 63;
    const int rowBase = (blockIdx.x * 4 + wave) * 16;
    if (rowBase >= N_NODES) return;

    const int m = rowBase + (lane & 15);
    const int kgrp = lane >> 4;
    const float* arow = (MODE == 0 ? A : (const float*)Fout) + (size_t)m * D;

    short8_t afrag[4];
    #pragma unroll
    for (int kc = 0; kc < 4; ++kc) {
        int k0 = kc * 32 + kgrp * 8;
        float4 lo = *(const float4*)(arow + k0);
        float4 hi = *(const float4*)(arow + k0 + 4);
        short8_t f;
        f[0] = (short)f32_to_bf16(lo.x);
        f[1] = (short)f32_to_bf16(lo.y);
        f[2] = (short)f32_to_bf16(lo.z);
        f[3] = (short)f32_to_bf16(lo.w);
        f[4] = (short)f32_to_bf16(hi.x);
        f[5] = (short)f32_to_bf16(hi.y);
        f[6] = (short)f32_to_bf16(hi.z);
        f[7] = (short)f32_to_bf16(hi.w);
        afrag[kc] = f;
    }

    floatx4 acc[8];
    #pragma unroll
    for (int nt = 0; nt < 8; ++nt)
        acc[nt] = (floatx4){0.f, 0.f, 0.f, 0.f};

    #pragma unroll
    for (int kc = 0; kc < 4; ++kc) {
        const int k0 = kc * 32 + kgrp * 8;
        #pragma unroll
        for (int nt = 0; nt < 8; ++nt) {
            const int n = nt * 16 + (lane & 15);
            short8_t b = *(const short8_t*)(&Ws[n][k0]);
            acc[nt] = __builtin_amdgcn_mfma_f32_16x16x32_bf16(afrag[kc], b, acc[nt], 0, 0, 0);
        }
    }

    const int orow0 = rowBase + (lane >> 4) * 4;
    const int col0 = lane & 15;
    if (MODE == 0) {
        #pragma unroll
        for (int j = 0; j < 4; ++j) {
            size_t base = (size_t)(orow0 + j) * D;
            #pragma unroll
            for (int nt = 0; nt < 8; ++nt)
                Ybf[base + nt * 16 + col0] = f32_to_bf16(acc[nt][j]);
        }
    } else {
        #pragma unroll
        for (int j = 0; j < 4; ++j) {
            size_t base = (size_t)(orow0 + j) * D;
            #pragma unroll
            for (int nt = 0; nt < 8; ++nt) {
                float v = acc[nt][j] + bc[nt * 16 + col0];
                Fout[base + nt * 16 + col0] = fmaxf(v, 0.f);
            }
        }
    }
}

// ---------------------------------------------------------------------------
// Fused per-bucket counting-sort + pull gather + bias + relu.
// R14 change: NO seg[] LDS staging — the bucket's ebuf segment (~3.3 KB,
// L2-resident) is read TWICE from global (pass 1 count, pass 2 place).
// LDS drops 25.6 KB -> 12.8 KB, lifting residency from 6 blocks/CU to the
// wave cap (8 blocks = 32 waves, 100%), restoring loads-in-flight for the
// latency-bound random 256 B row gathers (R14 measured: occ 38%, 2.57 TB/s).
// ---------------------------------------------------------------------------
__global__ __launch_bounds__(256)
void bucket_gather_k(const ushort_t* __restrict__ Ybf,
                     const unsigned* __restrict__ ebuf,
                     const int* __restrict__ bktbase,
                     const int* __restrict__ btot,
                     const float* __restrict__ bc,
                     float* __restrict__ out) {
    __shared__ unsigned slist[CAP];
    __shared__ int cnt64[64];      // per-node counts (pass 1, then read-only)
    __shared__ int start64[64];    // exclusive scan
    __shared__ int cur64[64];      // placement cursor
    const int bkt = blockIdx.x;
    const int t = threadIdx.x;
    const int base = bktbase[bkt];
    int cnt = btot[bkt];
    if (cnt > CAP) cnt = CAP;      // unreachable (79 sigma); OOB guard only

    if (t < 64) cnt64[t] = 0;
    __syncthreads();

    // pass 1: count (global read, coalesced, L2-resident)
    for (int i = t; i < cnt; i += 256)
        atomicAdd(&cnt64[ebuf[base + i] >> 24], 1);
    __syncthreads();

    // exclusive scan of 64 counts (wave 0)
    if (t < 64) {
        int v = cnt64[t];
        int s = v;
        #pragma unroll
        for (int d = 1; d < 64; d <<= 1) {
            int u = __shfl_up(s, d, 64);
            if (t >= d) s += u;
        }
        start64[t] = s - v;
        cur64[t] = s - v;
    }
    __syncthreads();

    // pass 2: place srcs in node order (re-read global, write LDS)
    for (int i = t; i < cnt; i += 256) {
        unsigned e = ebuf[base + i];
        int pos = atomicAdd(&cur64[e >> 24], 1);
        slist[pos] = e & 0xFFFFFFu;
    }
    __syncthreads();

    // gather: group g -> nodes v = g, g+8, ...
    const int g = t >> 5;
    const int l = t & 31;
    const int node0 = bkt * BSZ;
    float4 b4 = *(const float4*)(bc + l * 4);
    for (int v = g; v < BSZ; v += 8) {
        const int node = node0 + v;
        if (node >= N_NODES) break;          // only last bucket
        float4 acc;
        {
            ushort4 u = *(const ushort4*)(Ybf + (size_t)node * D + l * 4);
            acc.x = bf16_to_f32(u.x); acc.y = bf16_to_f32(u.y);
            acc.z = bf16_to_f32(u.z); acc.w = bf16_to_f32(u.w);
        }
        const int s = start64[v];
        const int e = s + cnt64[v];
        int k = s;
        for (; k + 1 < e; k += 2) {          // 2 rows in flight
            int n0 = slist[k];
            int n1 = slist[k + 1];
            ushort4 u0 = *(const ushort4*)(Ybf + (size_t)n0 * D + l * 4);
            ushort4 u1 = *(const ushort4*)(Ybf + (size_t)n1 * D + l * 4);
            acc.x += bf16_to_f32(u0.x); acc.y += bf16_to_f32(u0.y);
            acc.z += bf16_to_f32(u0.z); acc.w += bf16_to_f32(u0.w);
            acc.x += bf16_to_f32(u1.x); acc.y += bf16_to_f32(u1.y);
            acc.z += bf16_to_f32(u1.z); acc.w += bf16_to_f32(u1.w);
        }
        if (k < e) {
            int n0 = slist[k];
            ushort4 u0 = *(const ushort4*)(Ybf + (size_t)n0 * D + l * 4);
            acc.x += bf16_to_f32(u0.x); acc.y += bf16_to_f32(u0.y);
            acc.z += bf16_to_f32(u0.z); acc.w += bf16_to_f32(u0.w);
        }
        acc.x = fmaxf(acc.x + b4.x, 0.f);
        acc.y = fmaxf(acc.y + b4.y, 0.f);
        acc.z = fmaxf(acc.z + b4.z, 0.f);
        acc.w = fmaxf(acc.w + b4.w, 0.f);
        *(float4*)(out + (size_t)node * D + l * 4) = acc;
    }
}

// ===========================================================================
// Fallback path (small workspace): R8 CSR build + f32 gather + in-place GEMM
// ===========================================================================
__global__ __launch_bounds__(256)
void count_deg(const int* __restrict__ ra, const int* __restrict__ rb,
               int* __restrict__ cnt) {
    int e = blockIdx.x * 256 + threadIdx.x;
    if (e < N_EDGES) {
        atomicAdd(&cnt[ra[e]], 1);
        atomicAdd(&cnt[rb[e]], 1);
    }
}

__global__ __launch_bounds__(256)
void sum_blocks(const int* __restrict__ cnt, int* __restrict__ partials) {
    __shared__ int sm[256];
    int t = threadIdx.x;
    int base = blockIdx.x * 1024 + t * 4;
    int tot = 0;
    #pragma unroll
    for (int i = 0; i < 4; ++i)
        if (base + i < N_NODES) tot += cnt[base + i];
    sm[t] = tot;
    __syncthreads();
    for (int d = 128; d > 0; d >>= 1) {
        if (t < d) sm[t] += sm[t + d];
        __syncthreads();
    }
    if (t == 0) partials[blockIdx.x] = sm[0];
}

__global__ void scan_partials(int* __restrict__ partials, int* __restrict__ off) {
    if (blockIdx.x == 0 && threadIdx.x == 0) {
        int run = 0;
        for (int b = 0; b < NB; ++b) {
            int v = partials[b];
            partials[b] = run;
            run += v;
        }
        off[N_NODES] = run;
    }
}

__global__ __launch_bounds__(256)
void scan_blocks(const int* __restrict__ cnt, const int* __restrict__ partials,
                 int* __restrict__ off, int* __restrict__ cur) {
    __shared__ int sm[256];
    int t = threadIdx.x;
    int base = blockIdx.x * 1024 + t * 4;
    int c[4];
    int tot = 0;
    #pragma unroll
    for (int i = 0; i < 4; ++i) {
        c[i] = (base + i < N_NODES) ? cnt[base + i] : 0;
        tot += c[i];
    }
    sm[t] = tot;
    __syncthreads();
    for (int d = 1; d < 256; d <<= 1) {
        int v = (t >= d) ? sm[t - d] : 0;
        __syncthreads();
        sm[t] += v;
        __syncthreads();
    }
    int excl = sm[t] - tot + partials[blockIdx.x];
    #pragma unroll
    for (int i = 0; i < 4; ++i) {
        int idx = base + i;
        if (idx < N_NODES) {
            off[idx] = excl;
            cur[idx] = excl;
            excl += c[i];
        }
    }
}

__global__ __launch_bounds__(256)
void fill_adj(const int* __restrict__ ra, const int* __restrict__ rb,
              int* __restrict__ cur, int* __restrict__ adj) {
    int e = blockIdx.x * 256 + threadIdx.x;
    if (e < N_EDGES) {
        int a = ra[e];
        int b = rb[e];
        adj[atomicAdd(&cur[a], 1)] = b;
        adj[atomicAdd(&cur[b], 1)] = a;
    }
}

__global__ __launch_bounds__(256)
void gather_f32(const float* __restrict__ Xf, const int* __restrict__ off,
                const int* __restrict__ adj, float* __restrict__ out) {
    const int node = blockIdx.x * 8 + (threadIdx.x >> 5);
    const int lane = threadIdx.x & 31;
    float4 acc = *(const float4*)(Xf + (size_t)node * D + lane * 4);
    const int s = off[node];
    const int e = off[node + 1];
    int k = s;
    for (; k + 1 < e; k += 2) {
        int n0 = adj[k];
        int n1 = adj[k + 1];
        float4 v0 = *(const float4*)(Xf + (size_t)n0 * D + lane * 4);
        float4 v1 = *(const float4*)(Xf + (size_t)n1 * D + lane * 4);
        acc.x += v0.x; acc.y += v0.y; acc.z += v0.z; acc.w += v0.w;
        acc.x += v1.x; acc.y += v1.y; acc.z += v1.z; acc.w += v1.w;
    }
    if (k < e) {
        int n0 = adj[k];
        float4 v0 = *(const float4*)(Xf + (size_t)n0 * D + lane * 4);
        acc.x += v0.x; acc.y += v0.y; acc.z += v0.z; acc.w += v0.w;
    }
    *(float4*)(out + (size_t)node * D + lane * 4) = acc;
}

// ---------------------------------------------------------------------------
extern "C" void kernel_launch(void* const* d_in, const int* in_sizes, int n_in,
                              void* d_out, int out_size, void* d_ws, size_t ws_size,
                              hipStream_t stream) {
    const float* X  = (const float*)d_in[0];
    const float* Wh = (const float*)d_in[1];
    const float* bh = (const float*)d_in[2];
    const float* Wo = (const float*)d_in[3];
    const float* bo = (const float*)d_in[4];
    const int* ra   = (const int*)d_in[5];
    const int* rb   = (const int*)d_in[6];
    float* out = (float*)d_out;

    // workspace layout (main path) — ~30.4 MB, under R10's proven budget
    char* p = (char*)d_ws;
    ushort_t* WcT  = (ushort_t*)p; p += (size_t)D * D * 2;              // 32 KB
    float* bc      = (float*)p;    p += (size_t)D * 4;                  // 512 B
    int* hist      = (int*)p;      p += (size_t)NBLK_AC * NBKT_PAD * 4; // 401 KB
    int* btot      = (int*)p;      p += (size_t)NBKT_PAD * 4;           // 6.3 KB
    int* bktbase   = (int*)p;      p += (size_t)NBKT_PAD * 4;           // 6.3 KB
    unsigned* ebuf = (unsigned*)p; p += (size_t)2 * N_EDGES * 4;        // 5.12 MB
    ushort_t* Ybf  = (ushort_t*)p; p += (size_t)N_NODES * D * 2;        // 25.6 MB
    const size_t need = (size_t)(p - (char*)d_ws);
    const bool bigws = ws_size >= need;

    combine_weights<<<(D * D + D + 255) / 256, 256, 0, stream>>>(Wh, bh, Wo, bo, WcT, bc);

    if (bigws) {
        // GEMM-first: Y = bf16(X @ Wc)
        gemm_mfma<0><<<(N_NODES + 63) / 64, 256, 0, stream>>>(X, Ybf, nullptr, WcT, bc);
        // bucketed entry build (dense writes)
        hist_k<<<NBLK_AC, 1024, 0, stream>>>(ra, rb, hist);
        scan_hist_k<<<(NBKT + 3) / 4, 256, 0, stream>>>(hist, btot);
        scan_bkt_k<<<1, 64, 0, stream>>>(btot, bktbase);
        scatter_k<<<NBLK_AC, 1024, 0, stream>>>(ra, rb, hist, bktbase, ebuf);
        // fused sort (2-pass global) + pull gather + bias + relu
        bucket_gather_k<<<NBKT, 256, 0, stream>>>(Ybf, ebuf, bktbase, btot, bc, out);
    } else {
        // fallback: R8 CSR build + f32 gather into d_out + in-place MFMA GEMM
        char* q = (char*)d_ws;
        ushort_t* WcT2 = (ushort_t*)q; q += (size_t)D * D * 2;
        float* bc2     = (float*)q;    q += (size_t)D * 4;
        int* cnt       = (int*)q;      q += (size_t)N_NODES * 4;
        int* offF      = (int*)q;      q += (size_t)(N_NODES + 4) * 4;
        int* cur       = (int*)q;      q += (size_t)N_NODES * 4;
        int* adj       = (int*)q;      q += (size_t)2 * N_EDGES * 4;
        int* partials  = (int*)q;      q += 448;
        (void)WcT2; (void)bc2;
        hipMemsetAsync(cnt, 0, N_NODES * sizeof(int), stream);
        count_deg<<<N_EDGES / 256, 256, 0, stream>>>(ra, rb, cnt);
        sum_blocks<<<NB, 256, 0, stream>>>(cnt, partials);
        scan_partials<<<1, 64, 0, stream>>>(partials, offF);
        scan_blocks<<<NB, 256, 0, stream>>>(cnt, partials, offF, cur);
        fill_adj<<<N_EDGES / 256, 256, 0, stream>>>(ra, rb, cur, adj);
        gather_f32<<<N_NODES / 8, 256, 0, stream>>>(X, offF, adj, out);
        gemm_mfma<1><<<(N_NODES + 63) / 64, 256, 0, stream>>>(nullptr, nullptr, out, WcT, bc);
    }
}